// Round 5
// baseline (206.284 us; speedup 1.0000x reference)
//
#include <hip/hip_runtime.h>
#include <hip/hip_bf16.h>
#include <cstdint>
#include <cstddef>

#define CIN   512
#define COUT  512
#define LLEN  2048
#define BATCH 8
#define KTAP  8
#define LPAD  (LLEN + 8)   // 8 zero halo rows at the front of each batch

typedef __bf16 bf16x8_t __attribute__((ext_vector_type(8)));
typedef float  f32x4_t  __attribute__((ext_vector_type(4)));
typedef unsigned short u16x8_t __attribute__((ext_vector_type(8)));

__device__ __forceinline__ unsigned short f2bf(float f) {
  __bf16 h = (__bf16)f;                       // RNE fptrunc
  return __builtin_bit_cast(unsigned short, h);
}

__device__ __forceinline__ void gl2lds16(unsigned short* lds, const unsigned short* g) {
  __builtin_amdgcn_global_load_lds(
      (const __attribute__((address_space(1))) unsigned int*)g,
      (__attribute__((address_space(3))) unsigned int*)lds,
      16, 0, 0);
}

// ---------------- fused pre-pass (UNCHANGED) ----------------
// blocks [0, 2048): x (B,CIN,L) fp32 -> xtp (B, 8+L, CIN) bf16 transpose+cast
// blocks [2048, 3072): W (COUT*K, CIN) fp32 -> Wf bf16 FRAGMENT-MAJOR:
//   off16B = k*32768 + o128*8192 + wm*4096 + hg*2048 + ct*256 + i*64 + lane
__global__ __launch_bounds__(256) void prepass_kernel(
    const float* __restrict__ x, unsigned short* __restrict__ xtp,
    const float4* __restrict__ W, u16x8_t* __restrict__ Wf) {
  const int bid = blockIdx.x;
  const int t   = threadIdx.x;

  if (bid >= 2048) {                   // ---- W convert to fragment layout ----
    int idx = (bid - 2048) * 256 + t;  // 262144 chunks of 8 c-elems
    float4 a = W[idx * 2], b = W[idx * 2 + 1];
    u16x8_t o;
    o[0] = f2bf(a.x); o[1] = f2bf(a.y); o[2] = f2bf(a.z); o[3] = f2bf(a.w);
    o[4] = f2bf(b.x); o[5] = f2bf(b.y); o[6] = f2bf(b.z); o[7] = f2bf(b.w);
    const int row  = idx >> 6;         // k*COUT + o
    const int cch  = idx & 63;         // c chunk (8 elems)
    const int k    = row >> 9, oo = row & 511;
    const int o128 = oo >> 7, wm = (oo >> 6) & 1, fi = (oo >> 4) & 3, lrow = oo & 15;
    const int ct   = cch >> 3, chin = cch & 7, hg = chin >> 2, quad = chin & 3;
    const int lane = quad * 16 + lrow;
    const int off  = k * 32768 + o128 * 8192 + wm * 4096 + hg * 2048 +
                     ct * 256 + fi * 64 + lane;
    Wf[off] = o;
    return;
  }

  // ---- x transpose: 64(c) x 64(l) tile ----
  __shared__ float tile[64][65];
  const int b  = bid >> 8;             // 0..7
  const int c0 = ((bid >> 5) & 7) * 64;
  const int l0 = (bid & 31) * 64;

  if ((bid & 31) == 0 && t < 64) {     // halo zero: rows 0..7, cols c0..c0+63
    unsigned short* hp = xtp + ((size_t)b * LPAD + (t >> 3)) * CIN + c0 + (t & 7) * 8;
    *(u16x8_t*)hp = (u16x8_t){0, 0, 0, 0, 0, 0, 0, 0};
  }

  {
    const int cr = t >> 2;             // 0..63
    const int lv = (t & 3) * 16;       // 0,16,32,48
    const float* src = x + ((size_t)b * CIN + c0 + cr) * LLEN + l0 + lv;
#pragma unroll
    for (int i = 0; i < 4; ++i) {
      float4 v = *(const float4*)(src + 4 * i);
      tile[cr][lv + 4 * i + 0] = v.x;
      tile[cr][lv + 4 * i + 1] = v.y;
      tile[cr][lv + 4 * i + 2] = v.z;
      tile[cr][lv + 4 * i + 3] = v.w;
    }
  }
  __syncthreads();
  {
    const int l    = t >> 2;           // 0..63
    const int cseg = (t & 3) * 16;     // 0,16,32,48
    unsigned short ov[16];
#pragma unroll
    for (int u = 0; u < 16; ++u) ov[u] = f2bf(tile[cseg + u][l]);
    unsigned short* dst = xtp + ((size_t)b * LPAD + 8 + l0 + l) * CIN + c0 + cseg;
    *(u16x8_t*)dst       = *(const u16x8_t*)&ov[0];
    *(u16x8_t*)(dst + 8) = *(const u16x8_t*)&ov[8];
  }
}

// ---------------- fused conv GEMM ----------------
// R5 change (one mechanism): A-fragment loads are the exposed L2 latency on
// the critical path (R4 audit: ~60% all-wave-stall cycles; A traffic 18 TB/s
// -> loaded-L2 latency 400-600 cyc paid once per tap). Software-pipeline af
// ONE TAP AHEAD in registers (afbuf[2][4], statically unrolled k -> SSA
// renaming, no v_movs): tap k's MFMA cluster runs while tap k+1's A-loads
// are in flight; at k==7 the prefetch targets (ct+1, k=0) and flies over the
// __syncthreads (global load, barrier-independent). B path, staging, swizzle,
// hg-split, epilogue all unchanged from R4.

__global__ __launch_bounds__(512, 4) void conv_gemm_kernel(
    const unsigned short* __restrict__ Wf,   // fragment-major bf16 (4 MB)
    const unsigned short* __restrict__ xtp,  // (B, LPAD, CIN) bf16
    const float* __restrict__ bias,          // (COUT)
    float* __restrict__ y)                   // (B, COUT, LLEN) fp32
{
  // Bs[2]: 2 x 136*64 bf16 = 34 KB; epilogue scratch 64 KB fp32 aliased.
  __shared__ __align__(16) unsigned char smem[65536];

  const int t    = threadIdx.x;
  const int lane = t & 63;
  const int wid  = t >> 6;            // 0..7
  const int wm   = wid & 1;           // o half
  const int wn   = (wid >> 1) & 1;    // l half
  const int hg   = wid >> 2;          // K-half (c-chunks hg*4 .. hg*4+3)
  const int l0   = blockIdx.x * 128;
  const int o0   = blockIdx.y * 128;
  const int b    = blockIdx.z;

  const int quad = lane >> 4;
  const int lrow = lane & 15;

  unsigned short* BsBuf = (unsigned short*)smem;   // [buf * 8704]

  f32x4_t acc[4][4];
#pragma unroll
  for (int i = 0; i < 4; ++i)
#pragma unroll
    for (int j = 0; j < 4; ++j)
      acc[i][j] = (f32x4_t){0.f, 0.f, 0.f, 0.f};

  // B staging: rows of 64 bf16 = 8 chunks of 16 B; LDS slot s of row r holds
  // source chunk s ^ (r & 7) (swizzle applied on the SOURCE address).
  const int srow    = t >> 3;                       // 0..63 per round
  const int schunk  = (t & 7) ^ (srow & 7);         // swizzled source chunk
  const int lds_off = t * 8;                        // elements (t*16 bytes)

  const unsigned short* xb = xtp + (size_t)b * LPAD * CIN;

  auto stage_B = [&](int ct, int buf) {             // 128 rows = 2 rounds + halo
    const int c0 = ct * 64;
    const unsigned short* src = xb + (size_t)(l0 + srow) * CIN + c0 + schunk * 8;
#pragma unroll
    for (int rd = 0; rd < 2; ++rd)
      gl2lds16(BsBuf + buf * 8704 + lds_off + rd * 4096, src + (size_t)rd * 64 * CIN);
    if (t < 64) {
      const int r2  = 128 + (t >> 3);               // halo rows 128..135
      const int ch2 = (t & 7) ^ (r2 & 7);
      gl2lds16(BsBuf + buf * 8704 + 128 * 64 + t * 8,
               xb + (size_t)(l0 + r2) * CIN + c0 + ch2 * 8);
    }
  };

  const u16x8_t* Wfp = (const u16x8_t*)Wf;
  // per-wave fragment base (16B units): o128*8192 + wm*4096 + hg*2048 + lane
  const int woff = blockIdx.y * 8192 + wm * 4096 + hg * 2048 + lane;

  stage_B(0, 0);

  // A pipeline prologue: preload (ct=0, k=0) fragments
  bf16x8_t afbuf[2][4];
#pragma unroll
  for (int i = 0; i < 4; ++i)
    afbuf[0][i] = __builtin_bit_cast(bf16x8_t, Wfp[woff + i * 64]);

  __syncthreads();

#pragma unroll 1
  for (int ct = 0; ct < 8; ++ct) {
    if (ct + 1 < 8) stage_B(ct + 1, (ct + 1) & 1);  // in flight across 8 taps
    const unsigned short* Bc = BsBuf + (ct & 1) * 8704;
    const u16x8_t* wp = Wfp + woff + ct * 256;
#pragma unroll
    for (int k = 0; k < 8; ++k) {
      // ---- prefetch next tap's A (global; at k==7 targets ct+1, crosses
      //      the upcoming barrier legally) ----
      if (k < 7) {
#pragma unroll
        for (int i = 0; i < 4; ++i)
          afbuf[(k + 1) & 1][i] =
              __builtin_bit_cast(bf16x8_t, wp[(k + 1) * 32768 + i * 64]);
      } else if (ct + 1 < 8) {
#pragma unroll
        for (int i = 0; i < 4; ++i)
          afbuf[0][i] =
              __builtin_bit_cast(bf16x8_t, Wfp[woff + (ct + 1) * 256 + i * 64]);
      }
      // ---- B fragments for this tap (LDS) ----
      bf16x8_t bfr[4];
#pragma unroll
      for (int j = 0; j < 4; ++j) {
        int row  = (8 - k) + wn * 64 + j * 16 + lrow;   // halo shift
        int slot = (hg * 4 + quad) ^ (row & 7);
        bfr[j] = *(const bf16x8_t*)(Bc + row * 64 + slot * 8);
      }
      __builtin_amdgcn_s_setprio(1);
#pragma unroll
      for (int i = 0; i < 4; ++i)
#pragma unroll
        for (int j = 0; j < 4; ++j)
          acc[i][j] = __builtin_amdgcn_mfma_f32_16x16x32_bf16(
              afbuf[k & 1][i], bfr[j], acc[i][j], 0, 0, 0);
      __builtin_amdgcn_s_setprio(0);
    }
    __syncthreads();  // one barrier per ct chunk (8 total)
  }

  // ---- cross-hg reduction through LDS (alias smem; 16 KB per (wm,wn) pair) ----
  float* red = (float*)smem + (size_t)(wn * 2 + wm) * 4096;
  if (hg == 1) {
#pragma unroll
    for (int i = 0; i < 4; ++i)
#pragma unroll
      for (int j = 0; j < 4; ++j)
#pragma unroll
        for (int r = 0; r < 4; ++r)
          red[((i * 4 + j) * 4 + r) * 64 + lane] = acc[i][j][r];
  }
  __syncthreads();
  if (hg == 0) {
    // epilogue: D layout col = lane&15 (=l), row = quad*4+reg (=o)
#pragma unroll
    for (int i = 0; i < 4; ++i) {
      const int o_base = o0 + wm * 64 + i * 16 + quad * 4;
      const float4 bv = *(const float4*)(bias + o_base);
      const float bvr[4] = {bv.x, bv.y, bv.z, bv.w};
#pragma unroll
      for (int j = 0; j < 4; ++j) {
        const int l = l0 + wn * 64 + j * 16 + lrow;
#pragma unroll
        for (int r = 0; r < 4; ++r) {
          float v = acc[i][j][r] + red[((i * 4 + j) * 4 + r) * 64 + lane];
          y[((size_t)b * COUT + o_base + r) * LLEN + l] = v + bvr[r];
        }
      }
    }
  }
}

// ---------------- launch ----------------

extern "C" void kernel_launch(void* const* d_in, const int* in_sizes, int n_in,
                              void* d_out, int out_size, void* d_ws, size_t ws_size,
                              hipStream_t stream) {
  const float* x    = (const float*)d_in[0];   // (8, 512, 2048)
  const float* W    = (const float*)d_in[1];   // (4096, 512)
  const float* bias = (const float*)d_in[2];   // (512)
  float* y          = (float*)d_out;           // (8, 512, 2048)

  unsigned short* xtp = (unsigned short*)d_ws;                     // 16,842,752 B
  unsigned short* Wf  = (unsigned short*)((char*)d_ws +
                        (size_t)BATCH * LPAD * CIN * sizeof(unsigned short));

  prepass_kernel<<<2048 + 1024, 256, 0, stream>>>(
      x, xtp, (const float4*)W, (u16x8_t*)Wf);
  conv_gemm_kernel<<<dim3(LLEN / 128, COUT / 128, BATCH), 512, 0, stream>>>(
      Wf, xtp, bias, y);
}

// Round 6
// 154.222 us; speedup vs baseline: 1.3376x; 1.3376x over previous
//
#include <hip/hip_runtime.h>
#include <hip/hip_bf16.h>
#include <cstdint>
#include <cstddef>

#define CIN   512
#define COUT  512
#define LLEN  2048
#define BATCH 8
#define KTAP  8
#define LPAD  (LLEN + 8)   // 8 zero halo rows at the front of each batch

typedef __bf16 bf16x8_t __attribute__((ext_vector_type(8)));
typedef float  f32x4_t  __attribute__((ext_vector_type(4)));
typedef unsigned short u16x8_t __attribute__((ext_vector_type(8)));

__device__ __forceinline__ unsigned short f2bf(float f) {
  __bf16 h = (__bf16)f;                       // RNE fptrunc
  return __builtin_bit_cast(unsigned short, h);
}

__device__ __forceinline__ void gl2lds16(unsigned short* lds, const unsigned short* g) {
  __builtin_amdgcn_global_load_lds(
      (const __attribute__((address_space(1))) unsigned int*)g,
      (__attribute__((address_space(3))) unsigned int*)lds,
      16, 0, 0);
}

// ---------------- fused pre-pass (UNCHANGED) ----------------
// blocks [0, 2048): x (B,CIN,L) fp32 -> xtp (B, 8+L, CIN) bf16 transpose+cast
// blocks [2048, 3072): W (COUT*K, CIN) fp32 -> Wf bf16 FRAGMENT-MAJOR:
//   off16B = k*32768 + o128*8192 + wm*4096 + hg*2048 + ct*256 + i*64 + lane
__global__ __launch_bounds__(256) void prepass_kernel(
    const float* __restrict__ x, unsigned short* __restrict__ xtp,
    const float4* __restrict__ W, u16x8_t* __restrict__ Wf) {
  const int bid = blockIdx.x;
  const int t   = threadIdx.x;

  if (bid >= 2048) {                   // ---- W convert to fragment layout ----
    int idx = (bid - 2048) * 256 + t;  // 262144 chunks of 8 c-elems
    float4 a = W[idx * 2], b = W[idx * 2 + 1];
    u16x8_t o;
    o[0] = f2bf(a.x); o[1] = f2bf(a.y); o[2] = f2bf(a.z); o[3] = f2bf(a.w);
    o[4] = f2bf(b.x); o[5] = f2bf(b.y); o[6] = f2bf(b.z); o[7] = f2bf(b.w);
    const int row  = idx >> 6;         // k*COUT + o
    const int cch  = idx & 63;         // c chunk (8 elems)
    const int k    = row >> 9, oo = row & 511;
    const int o128 = oo >> 7, wm = (oo >> 6) & 1, fi = (oo >> 4) & 3, lrow = oo & 15;
    const int ct   = cch >> 3, chin = cch & 7, hg = chin >> 2, quad = chin & 3;
    const int lane = quad * 16 + lrow;
    const int off  = k * 32768 + o128 * 8192 + wm * 4096 + hg * 2048 +
                     ct * 256 + fi * 64 + lane;
    Wf[off] = o;
    return;
  }

  // ---- x transpose: 64(c) x 64(l) tile ----
  __shared__ float tile[64][65];
  const int b  = bid >> 8;             // 0..7
  const int c0 = ((bid >> 5) & 7) * 64;
  const int l0 = (bid & 31) * 64;

  if ((bid & 31) == 0 && t < 64) {     // halo zero: rows 0..7, cols c0..c0+63
    unsigned short* hp = xtp + ((size_t)b * LPAD + (t >> 3)) * CIN + c0 + (t & 7) * 8;
    *(u16x8_t*)hp = (u16x8_t){0, 0, 0, 0, 0, 0, 0, 0};
  }

  {
    const int cr = t >> 2;             // 0..63
    const int lv = (t & 3) * 16;       // 0,16,32,48
    const float* src = x + ((size_t)b * CIN + c0 + cr) * LLEN + l0 + lv;
#pragma unroll
    for (int i = 0; i < 4; ++i) {
      float4 v = *(const float4*)(src + 4 * i);
      tile[cr][lv + 4 * i + 0] = v.x;
      tile[cr][lv + 4 * i + 1] = v.y;
      tile[cr][lv + 4 * i + 2] = v.z;
      tile[cr][lv + 4 * i + 3] = v.w;
    }
  }
  __syncthreads();
  {
    const int l    = t >> 2;           // 0..63
    const int cseg = (t & 3) * 16;     // 0,16,32,48
    unsigned short ov[16];
#pragma unroll
    for (int u = 0; u < 16; ++u) ov[u] = f2bf(tile[cseg + u][l]);
    unsigned short* dst = xtp + ((size_t)b * LPAD + 8 + l0 + l) * CIN + c0 + cseg;
    *(u16x8_t*)dst       = *(const u16x8_t*)&ov[0];
    *(u16x8_t*)(dst + 8) = *(const u16x8_t*)&ov[8];
  }
}

// ---------------- fused conv GEMM ----------------
// R6: R5's one-tap-ahead A prefetch, but in a REGISTERIZABLE form. R5's
// afbuf[2][4] was demoted to scratch (FETCH 30->180 MB, WRITE 33->218 MB,
// VGPR stuck at 64 -- rule #20: the runtime-conditional write into afbuf[0]
// defeated SSA promotion). Fix: two NAMED arrays afA/afB, an explicit 8-step
// tap sequence with compile-time alternation, and NO conditional writes (the
// next-ct prefetch base wraps via (ct+1)&7 so the load/write is always
// executed; the ct=7 wrap reads valid memory redundantly). B path, staging,
// swizzle, hg-split, epilogue identical to R4.

__global__ __launch_bounds__(512, 4) void conv_gemm_kernel(
    const unsigned short* __restrict__ Wf,   // fragment-major bf16 (4 MB)
    const unsigned short* __restrict__ xtp,  // (B, LPAD, CIN) bf16
    const float* __restrict__ bias,          // (COUT)
    float* __restrict__ y)                   // (B, COUT, LLEN) fp32
{
  // Bs[2]: 2 x 136*64 bf16 = 34 KB; epilogue scratch 64 KB fp32 aliased.
  __shared__ __align__(16) unsigned char smem[65536];

  const int t    = threadIdx.x;
  const int lane = t & 63;
  const int wid  = t >> 6;            // 0..7
  const int wm   = wid & 1;           // o half
  const int wn   = (wid >> 1) & 1;    // l half
  const int hg   = wid >> 2;          // K-half (c-chunks hg*4 .. hg*4+3)
  const int l0   = blockIdx.x * 128;
  const int o0   = blockIdx.y * 128;
  const int b    = blockIdx.z;

  const int quad = lane >> 4;
  const int lrow = lane & 15;

  unsigned short* BsBuf = (unsigned short*)smem;   // [buf * 8704]

  f32x4_t acc[4][4];
#pragma unroll
  for (int i = 0; i < 4; ++i)
#pragma unroll
    for (int j = 0; j < 4; ++j)
      acc[i][j] = (f32x4_t){0.f, 0.f, 0.f, 0.f};

  // B staging: rows of 64 bf16 = 8 chunks of 16 B; LDS slot s of row r holds
  // source chunk s ^ (r & 7) (swizzle applied on the SOURCE address).
  const int srow    = t >> 3;                       // 0..63 per round
  const int schunk  = (t & 7) ^ (srow & 7);         // swizzled source chunk
  const int lds_off = t * 8;                        // elements (t*16 bytes)

  const unsigned short* xb = xtp + (size_t)b * LPAD * CIN;

  auto stage_B = [&](int ct, int buf) {             // 128 rows = 2 rounds + halo
    const int c0 = ct * 64;
    const unsigned short* src = xb + (size_t)(l0 + srow) * CIN + c0 + schunk * 8;
#pragma unroll
    for (int rd = 0; rd < 2; ++rd)
      gl2lds16(BsBuf + buf * 8704 + lds_off + rd * 4096, src + (size_t)rd * 64 * CIN);
    if (t < 64) {
      const int r2  = 128 + (t >> 3);               // halo rows 128..135
      const int ch2 = (t & 7) ^ (r2 & 7);
      gl2lds16(BsBuf + buf * 8704 + 128 * 64 + t * 8,
               xb + (size_t)(l0 + r2) * CIN + c0 + ch2 * 8);
    }
  };

  const u16x8_t* Wfp = (const u16x8_t*)Wf;
  // per-wave fragment base (16B units): o128*8192 + wm*4096 + hg*2048 + lane
  const int woff = blockIdx.y * 8192 + wm * 4096 + hg * 2048 + lane;

  stage_B(0, 0);

  // A pipeline prologue: preload (ct=0, k=0) fragments into afA
  bf16x8_t afA[4], afB[4];
#pragma unroll
  for (int i = 0; i < 4; ++i)
    afA[i] = __builtin_bit_cast(bf16x8_t, Wfp[woff + i * 64]);

  __syncthreads();

#pragma unroll 1
  for (int ct = 0; ct < 8; ++ct) {
    if (ct + 1 < 8) stage_B(ct + 1, (ct + 1) & 1);  // in flight across 8 taps
    const unsigned short* Bc = BsBuf + (ct & 1) * 8704;
    const u16x8_t* wp  = Wfp + woff + ct * 256;
    const u16x8_t* wpn = Wfp + woff + ((ct + 1) & 7) * 256;  // next-ct base (wraps)

    // one tap: prefetch NEXT tap's A into `nxt`, compute this tap with `cur`.
    // k is compile-time at each call site -> all indices literal constants.
    auto tap = [&](const int k, bf16x8_t (&cur)[4], bf16x8_t (&nxt)[4],
                   const u16x8_t* pf) {
#pragma unroll
      for (int i = 0; i < 4; ++i)
        nxt[i] = __builtin_bit_cast(bf16x8_t, pf[i * 64]);
      bf16x8_t bfr[4];
#pragma unroll
      for (int j = 0; j < 4; ++j) {
        int row  = (8 - k) + wn * 64 + j * 16 + lrow;   // halo shift
        int slot = (hg * 4 + quad) ^ (row & 7);
        bfr[j] = *(const bf16x8_t*)(Bc + row * 64 + slot * 8);
      }
      __builtin_amdgcn_s_setprio(1);
#pragma unroll
      for (int i = 0; i < 4; ++i)
#pragma unroll
        for (int j = 0; j < 4; ++j)
          acc[i][j] = __builtin_amdgcn_mfma_f32_16x16x32_bf16(
              cur[i], bfr[j], acc[i][j], 0, 0, 0);
      __builtin_amdgcn_s_setprio(0);
    };

    tap(0, afA, afB, wp + 1 * 32768);
    tap(1, afB, afA, wp + 2 * 32768);
    tap(2, afA, afB, wp + 3 * 32768);
    tap(3, afB, afA, wp + 4 * 32768);
    tap(4, afA, afB, wp + 5 * 32768);
    tap(5, afB, afA, wp + 6 * 32768);
    tap(6, afA, afB, wp + 7 * 32768);
    tap(7, afB, afA, wpn);            // prefetch next ct's k=0 into afA

    __syncthreads();  // one barrier per ct chunk (8 total)
  }

  // ---- cross-hg reduction through LDS (alias smem; 16 KB per (wm,wn) pair) ----
  float* red = (float*)smem + (size_t)(wn * 2 + wm) * 4096;
  if (hg == 1) {
#pragma unroll
    for (int i = 0; i < 4; ++i)
#pragma unroll
      for (int j = 0; j < 4; ++j)
#pragma unroll
        for (int r = 0; r < 4; ++r)
          red[((i * 4 + j) * 4 + r) * 64 + lane] = acc[i][j][r];
  }
  __syncthreads();
  if (hg == 0) {
    // epilogue: D layout col = lane&15 (=l), row = quad*4+reg (=o)
#pragma unroll
    for (int i = 0; i < 4; ++i) {
      const int o_base = o0 + wm * 64 + i * 16 + quad * 4;
      const float4 bv = *(const float4*)(bias + o_base);
      const float bvr[4] = {bv.x, bv.y, bv.z, bv.w};
#pragma unroll
      for (int j = 0; j < 4; ++j) {
        const int l = l0 + wn * 64 + j * 16 + lrow;
#pragma unroll
        for (int r = 0; r < 4; ++r) {
          float v = acc[i][j][r] + red[((i * 4 + j) * 4 + r) * 64 + lane];
          y[((size_t)b * COUT + o_base + r) * LLEN + l] = v + bvr[r];
        }
      }
    }
  }
}

// ---------------- launch ----------------

extern "C" void kernel_launch(void* const* d_in, const int* in_sizes, int n_in,
                              void* d_out, int out_size, void* d_ws, size_t ws_size,
                              hipStream_t stream) {
  const float* x    = (const float*)d_in[0];   // (8, 512, 2048)
  const float* W    = (const float*)d_in[1];   // (4096, 512)
  const float* bias = (const float*)d_in[2];   // (512)
  float* y          = (float*)d_out;           // (8, 512, 2048)

  unsigned short* xtp = (unsigned short*)d_ws;                     // 16,842,752 B
  unsigned short* Wf  = (unsigned short*)((char*)d_ws +
                        (size_t)BATCH * LPAD * CIN * sizeof(unsigned short));

  prepass_kernel<<<2048 + 1024, 256, 0, stream>>>(
      x, xtp, (const float4*)W, (u16x8_t*)Wf);
  conv_gemm_kernel<<<dim3(LLEN / 128, COUT / 128, BATCH), 512, 0, stream>>>(
      Wf, xtp, bias, y);
}

// Round 7
// 147.175 us; speedup vs baseline: 1.4016x; 1.0479x over previous
//
#include <hip/hip_runtime.h>
#include <hip/hip_bf16.h>
#include <cstdint>
#include <cstddef>

#define CIN   512
#define COUT  512
#define LLEN  2048
#define BATCH 8
#define KTAP  8
#define LPAD  (LLEN + 8)   // 8 zero halo rows at the front of each batch

typedef __bf16 bf16x8_t __attribute__((ext_vector_type(8)));
typedef float  f32x4_t  __attribute__((ext_vector_type(4)));
typedef unsigned short u16x8_t __attribute__((ext_vector_type(8)));

__device__ __forceinline__ unsigned short f2bf(float f) {
  __bf16 h = (__bf16)f;                       // RNE fptrunc
  return __builtin_bit_cast(unsigned short, h);
}

__device__ __forceinline__ void gl2lds16(unsigned short* lds, const unsigned short* g) {
  __builtin_amdgcn_global_load_lds(
      (const __attribute__((address_space(1))) unsigned int*)g,
      (__attribute__((address_space(3))) unsigned int*)lds,
      16, 0, 0);
}

// ---------------- fused pre-pass (UNCHANGED) ----------------
// blocks [0, 2048): x (B,CIN,L) fp32 -> xtp (B, 8+L, CIN) bf16 transpose+cast
// blocks [2048, 3072): W (COUT*K, CIN) fp32 -> Wf bf16 FRAGMENT-MAJOR:
//   off16B = k*32768 + o128*8192 + wm*4096 + hg*2048 + ct*256 + i*64 + lane
__global__ __launch_bounds__(256) void prepass_kernel(
    const float* __restrict__ x, unsigned short* __restrict__ xtp,
    const float4* __restrict__ W, u16x8_t* __restrict__ Wf) {
  const int bid = blockIdx.x;
  const int t   = threadIdx.x;

  if (bid >= 2048) {                   // ---- W convert to fragment layout ----
    int idx = (bid - 2048) * 256 + t;  // 262144 chunks of 8 c-elems
    float4 a = W[idx * 2], b = W[idx * 2 + 1];
    u16x8_t o;
    o[0] = f2bf(a.x); o[1] = f2bf(a.y); o[2] = f2bf(a.z); o[3] = f2bf(a.w);
    o[4] = f2bf(b.x); o[5] = f2bf(b.y); o[6] = f2bf(b.z); o[7] = f2bf(b.w);
    const int row  = idx >> 6;         // k*COUT + o
    const int cch  = idx & 63;         // c chunk (8 elems)
    const int k    = row >> 9, oo = row & 511;
    const int o128 = oo >> 7, wm = (oo >> 6) & 1, fi = (oo >> 4) & 3, lrow = oo & 15;
    const int ct   = cch >> 3, chin = cch & 7, hg = chin >> 2, quad = chin & 3;
    const int lane = quad * 16 + lrow;
    const int off  = k * 32768 + o128 * 8192 + wm * 4096 + hg * 2048 +
                     ct * 256 + fi * 64 + lane;
    Wf[off] = o;
    return;
  }

  // ---- x transpose: 64(c) x 64(l) tile ----
  __shared__ float tile[64][65];
  const int b  = bid >> 8;             // 0..7
  const int c0 = ((bid >> 5) & 7) * 64;
  const int l0 = (bid & 31) * 64;

  if ((bid & 31) == 0 && t < 64) {     // halo zero: rows 0..7, cols c0..c0+63
    unsigned short* hp = xtp + ((size_t)b * LPAD + (t >> 3)) * CIN + c0 + (t & 7) * 8;
    *(u16x8_t*)hp = (u16x8_t){0, 0, 0, 0, 0, 0, 0, 0};
  }

  {
    const int cr = t >> 2;             // 0..63
    const int lv = (t & 3) * 16;       // 0,16,32,48
    const float* src = x + ((size_t)b * CIN + c0 + cr) * LLEN + l0 + lv;
#pragma unroll
    for (int i = 0; i < 4; ++i) {
      float4 v = *(const float4*)(src + 4 * i);
      tile[cr][lv + 4 * i + 0] = v.x;
      tile[cr][lv + 4 * i + 1] = v.y;
      tile[cr][lv + 4 * i + 2] = v.z;
      tile[cr][lv + 4 * i + 3] = v.w;
    }
  }
  __syncthreads();
  {
    const int l    = t >> 2;           // 0..63
    const int cseg = (t & 3) * 16;     // 0,16,32,48
    unsigned short ov[16];
#pragma unroll
    for (int u = 0; u < 16; ++u) ov[u] = f2bf(tile[cseg + u][l]);
    unsigned short* dst = xtp + ((size_t)b * LPAD + 8 + l0 + l) * CIN + c0 + cseg;
    *(u16x8_t*)dst       = *(const u16x8_t*)&ov[0];
    *(u16x8_t*)(dst + 8) = *(const u16x8_t*)&ov[8];
  }
}

// ---------------- fused conv GEMM ----------------
// R7: one-tap-ahead A prefetch in a SPILL-PROOF form. R6 still spilled
// (FETCH 44.7 / WRITE 53 MB vs clean 30/33): launch_bounds(512,4) caps the
// unified file at 128 VGPR and acc(64)+afA(16)+afB(16)+bfr(16)+addr regs
// blew the budget; lambda array-reference params also block SROA. Fix:
// (1) eight individually NAMED bf16x8_t (a0..a3 / b0..b3), macro-expanded
// 8-tap sequence, every index a literal -> guaranteed SSA/registers;
// (2) B fragments streamed ONE AT A TIME (bfj) inside the MFMA cluster
// (frees ~12 live VGPRs -> total ~116 <= 128). Tap k issues the 4 A-loads
// for tap k+1, then computes; tap 7 prefetches (ct+1)&7's k=0 (wrap read is
// harmless). B path / staging / swizzle / hg-split / epilogue = R4.

__global__ __launch_bounds__(512, 4) void conv_gemm_kernel(
    const unsigned short* __restrict__ Wf,   // fragment-major bf16 (4 MB)
    const unsigned short* __restrict__ xtp,  // (B, LPAD, CIN) bf16
    const float* __restrict__ bias,          // (COUT)
    float* __restrict__ y)                   // (B, COUT, LLEN) fp32
{
  // Bs[2]: 2 x 136*64 bf16 = 34 KB; epilogue scratch 64 KB fp32 aliased.
  __shared__ __align__(16) unsigned char smem[65536];

  const int t    = threadIdx.x;
  const int lane = t & 63;
  const int wid  = t >> 6;            // 0..7
  const int wm   = wid & 1;           // o half
  const int wn   = (wid >> 1) & 1;    // l half
  const int hg   = wid >> 2;          // K-half (c-chunks hg*4 .. hg*4+3)
  const int l0   = blockIdx.x * 128;
  const int o0   = blockIdx.y * 128;
  const int b    = blockIdx.z;

  const int quad = lane >> 4;
  const int lrow = lane & 15;

  unsigned short* BsBuf = (unsigned short*)smem;   // [buf * 8704]

  f32x4_t acc[4][4];
#pragma unroll
  for (int i = 0; i < 4; ++i)
#pragma unroll
    for (int j = 0; j < 4; ++j)
      acc[i][j] = (f32x4_t){0.f, 0.f, 0.f, 0.f};

  // B staging: rows of 64 bf16 = 8 chunks of 16 B; LDS slot s of row r holds
  // source chunk s ^ (r & 7) (swizzle applied on the SOURCE address).
  const int srow    = t >> 3;                       // 0..63 per round
  const int schunk  = (t & 7) ^ (srow & 7);         // swizzled source chunk
  const int lds_off = t * 8;                        // elements (t*16 bytes)

  const unsigned short* xb = xtp + (size_t)b * LPAD * CIN;

  auto stage_B = [&](int ct, int buf) {             // 128 rows = 2 rounds + halo
    const int c0 = ct * 64;
    const unsigned short* src = xb + (size_t)(l0 + srow) * CIN + c0 + schunk * 8;
#pragma unroll
    for (int rd = 0; rd < 2; ++rd)
      gl2lds16(BsBuf + buf * 8704 + lds_off + rd * 4096, src + (size_t)rd * 64 * CIN);
    if (t < 64) {
      const int r2  = 128 + (t >> 3);               // halo rows 128..135
      const int ch2 = (t & 7) ^ (r2 & 7);
      gl2lds16(BsBuf + buf * 8704 + 128 * 64 + t * 8,
               xb + (size_t)(l0 + r2) * CIN + c0 + ch2 * 8);
    }
  };

  const u16x8_t* Wfp = (const u16x8_t*)Wf;
  // per-wave fragment base (16B units): o128*8192 + wm*4096 + hg*2048 + lane
  const int woff = blockIdx.y * 8192 + wm * 4096 + hg * 2048 + lane;

  stage_B(0, 0);

  // A pipeline prologue: preload (ct=0, k=0) fragments into a0..a3
  bf16x8_t a0, a1, a2, a3, b0, b1, b2, b3;
  a0 = __builtin_bit_cast(bf16x8_t, Wfp[woff + 0 * 64]);
  a1 = __builtin_bit_cast(bf16x8_t, Wfp[woff + 1 * 64]);
  a2 = __builtin_bit_cast(bf16x8_t, Wfp[woff + 2 * 64]);
  a3 = __builtin_bit_cast(bf16x8_t, Wfp[woff + 3 * 64]);

  __syncthreads();

// one tap: issue next tap's 4 A-loads (n0..n3), then stream B per-j with a
// 4-MFMA cluster per fragment. All names/indices compile-time -> pure SSA.
#define TAP(kk, c0_, c1_, c2_, c3_, n0_, n1_, n2_, n3_, pfbase)              \
  {                                                                          \
    n0_ = __builtin_bit_cast(bf16x8_t, (pfbase)[0 * 64]);                    \
    n1_ = __builtin_bit_cast(bf16x8_t, (pfbase)[1 * 64]);                    \
    n2_ = __builtin_bit_cast(bf16x8_t, (pfbase)[2 * 64]);                    \
    n3_ = __builtin_bit_cast(bf16x8_t, (pfbase)[3 * 64]);                    \
    __builtin_amdgcn_s_setprio(1);                                           \
    _Pragma("unroll")                                                        \
    for (int j = 0; j < 4; ++j) {                                            \
      int row  = (8 - (kk)) + wn * 64 + j * 16 + lrow;                       \
      int slot = (hg * 4 + quad) ^ (row & 7);                                \
      bf16x8_t bfj = *(const bf16x8_t*)(Bc + row * 64 + slot * 8);           \
      acc[0][j] = __builtin_amdgcn_mfma_f32_16x16x32_bf16(c0_, bfj, acc[0][j], 0, 0, 0); \
      acc[1][j] = __builtin_amdgcn_mfma_f32_16x16x32_bf16(c1_, bfj, acc[1][j], 0, 0, 0); \
      acc[2][j] = __builtin_amdgcn_mfma_f32_16x16x32_bf16(c2_, bfj, acc[2][j], 0, 0, 0); \
      acc[3][j] = __builtin_amdgcn_mfma_f32_16x16x32_bf16(c3_, bfj, acc[3][j], 0, 0, 0); \
    }                                                                        \
    __builtin_amdgcn_s_setprio(0);                                           \
  }

#pragma unroll 1
  for (int ct = 0; ct < 8; ++ct) {
    if (ct + 1 < 8) stage_B(ct + 1, (ct + 1) & 1);  // in flight across 8 taps
    const unsigned short* Bc = BsBuf + (ct & 1) * 8704;
    const u16x8_t* wp  = Wfp + woff + ct * 256;
    const u16x8_t* wpn = Wfp + woff + ((ct + 1) & 7) * 256;  // next-ct base (wraps)

    TAP(0, a0, a1, a2, a3, b0, b1, b2, b3, wp + 1 * 32768)
    TAP(1, b0, b1, b2, b3, a0, a1, a2, a3, wp + 2 * 32768)
    TAP(2, a0, a1, a2, a3, b0, b1, b2, b3, wp + 3 * 32768)
    TAP(3, b0, b1, b2, b3, a0, a1, a2, a3, wp + 4 * 32768)
    TAP(4, a0, a1, a2, a3, b0, b1, b2, b3, wp + 5 * 32768)
    TAP(5, b0, b1, b2, b3, a0, a1, a2, a3, wp + 6 * 32768)
    TAP(6, a0, a1, a2, a3, b0, b1, b2, b3, wp + 7 * 32768)
    TAP(7, b0, b1, b2, b3, a0, a1, a2, a3, wpn)     // next ct's k=0 -> a0..a3

    __syncthreads();  // one barrier per ct chunk (8 total)
  }
#undef TAP

  // ---- cross-hg reduction through LDS (alias smem; 16 KB per (wm,wn) pair) ----
  float* red = (float*)smem + (size_t)(wn * 2 + wm) * 4096;
  if (hg == 1) {
#pragma unroll
    for (int i = 0; i < 4; ++i)
#pragma unroll
      for (int j = 0; j < 4; ++j)
#pragma unroll
        for (int r = 0; r < 4; ++r)
          red[((i * 4 + j) * 4 + r) * 64 + lane] = acc[i][j][r];
  }
  __syncthreads();
  if (hg == 0) {
    // epilogue: D layout col = lane&15 (=l), row = quad*4+reg (=o)
#pragma unroll
    for (int i = 0; i < 4; ++i) {
      const int o_base = o0 + wm * 64 + i * 16 + quad * 4;
      const float4 bv = *(const float4*)(bias + o_base);
      const float bvr[4] = {bv.x, bv.y, bv.z, bv.w};
#pragma unroll
      for (int j = 0; j < 4; ++j) {
        const int l = l0 + wn * 64 + j * 16 + lrow;
#pragma unroll
        for (int r = 0; r < 4; ++r) {
          float v = acc[i][j][r] + red[((i * 4 + j) * 4 + r) * 64 + lane];
          y[((size_t)b * COUT + o_base + r) * LLEN + l] = v + bvr[r];
        }
      }
    }
  }
}

// ---------------- launch ----------------

extern "C" void kernel_launch(void* const* d_in, const int* in_sizes, int n_in,
                              void* d_out, int out_size, void* d_ws, size_t ws_size,
                              hipStream_t stream) {
  const float* x    = (const float*)d_in[0];   // (8, 512, 2048)
  const float* W    = (const float*)d_in[1];   // (4096, 512)
  const float* bias = (const float*)d_in[2];   // (512)
  float* y          = (float*)d_out;           // (8, 512, 2048)

  unsigned short* xtp = (unsigned short*)d_ws;                     // 16,842,752 B
  unsigned short* Wf  = (unsigned short*)((char*)d_ws +
                        (size_t)BATCH * LPAD * CIN * sizeof(unsigned short));

  prepass_kernel<<<2048 + 1024, 256, 0, stream>>>(
      x, xtp, (const float4*)W, (u16x8_t*)Wf);
  conv_gemm_kernel<<<dim3(LLEN / 128, COUT / 128, BATCH), 512, 0, stream>>>(
      Wf, xtp, bias, y);
}

// Round 8
// 146.134 us; speedup vs baseline: 1.4116x; 1.0071x over previous
//
#include <hip/hip_runtime.h>
#include <hip/hip_bf16.h>
#include <cstdint>
#include <cstddef>

#define CIN   512
#define COUT  512
#define LLEN  2048
#define BATCH 8
#define KTAP  8
#define LPAD  (LLEN + 8)   // 8 zero halo rows at the front of each batch

typedef __bf16 bf16x8_t __attribute__((ext_vector_type(8)));
typedef float  f32x4_t  __attribute__((ext_vector_type(4)));
typedef unsigned short u16x8_t __attribute__((ext_vector_type(8)));

__device__ __forceinline__ unsigned short f2bf(float f) {
  __bf16 h = (__bf16)f;                       // RNE fptrunc
  return __builtin_bit_cast(unsigned short, h);
}

__device__ __forceinline__ void gl2lds16(unsigned short* lds, const unsigned short* g) {
  __builtin_amdgcn_global_load_lds(
      (const __attribute__((address_space(1))) unsigned int*)g,
      (__attribute__((address_space(3))) unsigned int*)lds,
      16, 0, 0);
}

// ---------------- fused pre-pass (REWRITTEN x-part for throughput) ----------------
// blocks [0, 512): x (B,CIN,L) fp32 -> xtp (B, 8+L, CIN) bf16 transpose+cast.
//   Each block: 64(c) x 256(l), processed as 2 phase-pairs of 64c x 128l.
//   float4 LDS writes (4x fewer LDS instrs), stride-140 float padding
//   (2-way bank aliasing only = free), 8 independent global loads/thread.
// blocks [512, 1536): W (COUT*K, CIN) fp32 -> Wf bf16 FRAGMENT-MAJOR (unchanged):
//   off16B = k*32768 + o128*8192 + wm*4096 + hg*2048 + ct*256 + i*64 + lane
__global__ __launch_bounds__(256) void prepass_kernel(
    const float* __restrict__ x, unsigned short* __restrict__ xtp,
    const float4* __restrict__ W, u16x8_t* __restrict__ Wf) {
  const int bid = blockIdx.x;
  const int t   = threadIdx.x;

  if (bid >= 512) {                    // ---- W convert to fragment layout ----
    int idx = (bid - 512) * 256 + t;   // 262144 chunks of 8 c-elems
    float4 a = W[idx * 2], b = W[idx * 2 + 1];
    u16x8_t o;
    o[0] = f2bf(a.x); o[1] = f2bf(a.y); o[2] = f2bf(a.z); o[3] = f2bf(a.w);
    o[4] = f2bf(b.x); o[5] = f2bf(b.y); o[6] = f2bf(b.z); o[7] = f2bf(b.w);
    const int row  = idx >> 6;         // k*COUT + o
    const int cch  = idx & 63;         // c chunk (8 elems)
    const int k    = row >> 9, oo = row & 511;
    const int o128 = oo >> 7, wm = (oo >> 6) & 1, fi = (oo >> 4) & 3, lrow = oo & 15;
    const int ct   = cch >> 3, chin = cch & 7, hg = chin >> 2, quad = chin & 3;
    const int lane = quad * 16 + lrow;
    const int off  = k * 32768 + o128 * 8192 + wm * 4096 + hg * 2048 +
                     ct * 256 + fi * 64 + lane;
    Wf[off] = o;
    return;
  }

  // ---- x transpose: 64(c) x 256(l) per block ----
  __shared__ float tile[64][140];      // stride 140: 16B-aligned, 2-way banks
  const int b     = bid >> 6;          // 0..7
  const int rem   = bid & 63;
  const int c0    = (rem >> 3) * 64;   // 8 c-chunks
  const int lbase = (rem & 7) * 256;   // 8 l-chunks of 256

  if ((rem & 7) == 0 && t < 64) {      // halo zero: rows 0..7, cols c0..c0+63
    unsigned short* hp = xtp + ((size_t)b * LPAD + (t >> 3)) * CIN + c0 + (t & 7) * 8;
    *(u16x8_t*)hp = (u16x8_t){0, 0, 0, 0, 0, 0, 0, 0};
  }

#pragma unroll 1
  for (int p = 0; p < 2; ++p) {
    const int l0 = lbase + p * 128;
    {
      const int cr = t >> 2;           // 0..63
      const float* srcp = x + ((size_t)b * CIN + c0 + cr) * LLEN + l0;
#pragma unroll
      for (int i = 0; i < 8; ++i) {    // 8 independent float4 loads
        float4 v = *(const float4*)(srcp + ((t & 3) + 4 * i) * 4);
        *(float4*)&tile[cr][((t & 3) + 4 * i) * 4] = v;
      }
    }
    __syncthreads();
    {
      const int l    = t >> 1;         // 0..127
      const int cseg = (t & 1) * 32;   // 0 or 32
      unsigned short ov[32];
#pragma unroll
      for (int u = 0; u < 32; ++u) ov[u] = f2bf(tile[cseg + u][l]);
      unsigned short* dst = xtp + ((size_t)b * LPAD + 8 + l0 + l) * CIN + c0 + cseg;
      *(u16x8_t*)(dst)      = *(const u16x8_t*)&ov[0];
      *(u16x8_t*)(dst + 8)  = *(const u16x8_t*)&ov[8];
      *(u16x8_t*)(dst + 16) = *(const u16x8_t*)&ov[16];
      *(u16x8_t*)(dst + 24) = *(const u16x8_t*)&ov[24];
    }
    __syncthreads();
  }
}

// ---------------- fused conv GEMM (byte-identical to R7 -- control) ----------------
// C[o][l] (128x128 per block) = sum_k sum_c W[k*COUT+o][c] * xT[l-k][c].
// One-tap-ahead A prefetch via named SSA vars; B streamed per-j from LDS;
// 8 barriers total; hg-split + LDS reduction epilogue.

__global__ __launch_bounds__(512, 4) void conv_gemm_kernel(
    const unsigned short* __restrict__ Wf,   // fragment-major bf16 (4 MB)
    const unsigned short* __restrict__ xtp,  // (B, LPAD, CIN) bf16
    const float* __restrict__ bias,          // (COUT)
    float* __restrict__ y)                   // (B, COUT, LLEN) fp32
{
  // Bs[2]: 2 x 136*64 bf16 = 34 KB; epilogue scratch 64 KB fp32 aliased.
  __shared__ __align__(16) unsigned char smem[65536];

  const int t    = threadIdx.x;
  const int lane = t & 63;
  const int wid  = t >> 6;            // 0..7
  const int wm   = wid & 1;           // o half
  const int wn   = (wid >> 1) & 1;    // l half
  const int hg   = wid >> 2;          // K-half (c-chunks hg*4 .. hg*4+3)
  const int l0   = blockIdx.x * 128;
  const int o0   = blockIdx.y * 128;
  const int b    = blockIdx.z;

  const int quad = lane >> 4;
  const int lrow = lane & 15;

  unsigned short* BsBuf = (unsigned short*)smem;   // [buf * 8704]

  f32x4_t acc[4][4];
#pragma unroll
  for (int i = 0; i < 4; ++i)
#pragma unroll
    for (int j = 0; j < 4; ++j)
      acc[i][j] = (f32x4_t){0.f, 0.f, 0.f, 0.f};

  // B staging: rows of 64 bf16 = 8 chunks of 16 B; LDS slot s of row r holds
  // source chunk s ^ (r & 7) (swizzle applied on the SOURCE address).
  const int srow    = t >> 3;                       // 0..63 per round
  const int schunk  = (t & 7) ^ (srow & 7);         // swizzled source chunk
  const int lds_off = t * 8;                        // elements (t*16 bytes)

  const unsigned short* xb = xtp + (size_t)b * LPAD * CIN;

  auto stage_B = [&](int ct, int buf) {             // 128 rows = 2 rounds + halo
    const int c0 = ct * 64;
    const unsigned short* src = xb + (size_t)(l0 + srow) * CIN + c0 + schunk * 8;
#pragma unroll
    for (int rd = 0; rd < 2; ++rd)
      gl2lds16(BsBuf + buf * 8704 + lds_off + rd * 4096, src + (size_t)rd * 64 * CIN);
    if (t < 64) {
      const int r2  = 128 + (t >> 3);               // halo rows 128..135
      const int ch2 = (t & 7) ^ (r2 & 7);
      gl2lds16(BsBuf + buf * 8704 + 128 * 64 + t * 8,
               xb + (size_t)(l0 + r2) * CIN + c0 + ch2 * 8);
    }
  };

  const u16x8_t* Wfp = (const u16x8_t*)Wf;
  // per-wave fragment base (16B units): o128*8192 + wm*4096 + hg*2048 + lane
  const int woff = blockIdx.y * 8192 + wm * 4096 + hg * 2048 + lane;

  stage_B(0, 0);

  // A pipeline prologue: preload (ct=0, k=0) fragments into a0..a3
  bf16x8_t a0, a1, a2, a3, b0, b1, b2, b3;
  a0 = __builtin_bit_cast(bf16x8_t, Wfp[woff + 0 * 64]);
  a1 = __builtin_bit_cast(bf16x8_t, Wfp[woff + 1 * 64]);
  a2 = __builtin_bit_cast(bf16x8_t, Wfp[woff + 2 * 64]);
  a3 = __builtin_bit_cast(bf16x8_t, Wfp[woff + 3 * 64]);

  __syncthreads();

// one tap: issue next tap's 4 A-loads (n0..n3), then stream B per-j with a
// 4-MFMA cluster per fragment. All names/indices compile-time -> pure SSA.
#define TAP(kk, c0_, c1_, c2_, c3_, n0_, n1_, n2_, n3_, pfbase)              \
  {                                                                          \
    n0_ = __builtin_bit_cast(bf16x8_t, (pfbase)[0 * 64]);                    \
    n1_ = __builtin_bit_cast(bf16x8_t, (pfbase)[1 * 64]);                    \
    n2_ = __builtin_bit_cast(bf16x8_t, (pfbase)[2 * 64]);                    \
    n3_ = __builtin_bit_cast(bf16x8_t, (pfbase)[3 * 64]);                    \
    __builtin_amdgcn_s_setprio(1);                                           \
    _Pragma("unroll")                                                        \
    for (int j = 0; j < 4; ++j) {                                            \
      int row  = (8 - (kk)) + wn * 64 + j * 16 + lrow;                       \
      int slot = (hg * 4 + quad) ^ (row & 7);                                \
      bf16x8_t bfj = *(const bf16x8_t*)(Bc + row * 64 + slot * 8);           \
      acc[0][j] = __builtin_amdgcn_mfma_f32_16x16x32_bf16(c0_, bfj, acc[0][j], 0, 0, 0); \
      acc[1][j] = __builtin_amdgcn_mfma_f32_16x16x32_bf16(c1_, bfj, acc[1][j], 0, 0, 0); \
      acc[2][j] = __builtin_amdgcn_mfma_f32_16x16x32_bf16(c2_, bfj, acc[2][j], 0, 0, 0); \
      acc[3][j] = __builtin_amdgcn_mfma_f32_16x16x32_bf16(c3_, bfj, acc[3][j], 0, 0, 0); \
    }                                                                        \
    __builtin_amdgcn_s_setprio(0);                                           \
  }

#pragma unroll 1
  for (int ct = 0; ct < 8; ++ct) {
    if (ct + 1 < 8) stage_B(ct + 1, (ct + 1) & 1);  // in flight across 8 taps
    const unsigned short* Bc = BsBuf + (ct & 1) * 8704;
    const u16x8_t* wp  = Wfp + woff + ct * 256;
    const u16x8_t* wpn = Wfp + woff + ((ct + 1) & 7) * 256;  // next-ct base (wraps)

    TAP(0, a0, a1, a2, a3, b0, b1, b2, b3, wp + 1 * 32768)
    TAP(1, b0, b1, b2, b3, a0, a1, a2, a3, wp + 2 * 32768)
    TAP(2, a0, a1, a2, a3, b0, b1, b2, b3, wp + 3 * 32768)
    TAP(3, b0, b1, b2, b3, a0, a1, a2, a3, wp + 4 * 32768)
    TAP(4, a0, a1, a2, a3, b0, b1, b2, b3, wp + 5 * 32768)
    TAP(5, b0, b1, b2, b3, a0, a1, a2, a3, wp + 6 * 32768)
    TAP(6, a0, a1, a2, a3, b0, b1, b2, b3, wp + 7 * 32768)
    TAP(7, b0, b1, b2, b3, a0, a1, a2, a3, wpn)     // next ct's k=0 -> a0..a3

    __syncthreads();  // one barrier per ct chunk (8 total)
  }
#undef TAP

  // ---- cross-hg reduction through LDS (alias smem; 16 KB per (wm,wn) pair) ----
  float* red = (float*)smem + (size_t)(wn * 2 + wm) * 4096;
  if (hg == 1) {
#pragma unroll
    for (int i = 0; i < 4; ++i)
#pragma unroll
      for (int j = 0; j < 4; ++j)
#pragma unroll
        for (int r = 0; r < 4; ++r)
          red[((i * 4 + j) * 4 + r) * 64 + lane] = acc[i][j][r];
  }
  __syncthreads();
  if (hg == 0) {
    // epilogue: D layout col = lane&15 (=l), row = quad*4+reg (=o)
#pragma unroll
    for (int i = 0; i < 4; ++i) {
      const int o_base = o0 + wm * 64 + i * 16 + quad * 4;
      const float4 bv = *(const float4*)(bias + o_base);
      const float bvr[4] = {bv.x, bv.y, bv.z, bv.w};
#pragma unroll
      for (int j = 0; j < 4; ++j) {
        const int l = l0 + wn * 64 + j * 16 + lrow;
#pragma unroll
        for (int r = 0; r < 4; ++r) {
          float v = acc[i][j][r] + red[((i * 4 + j) * 4 + r) * 64 + lane];
          y[((size_t)b * COUT + o_base + r) * LLEN + l] = v + bvr[r];
        }
      }
    }
  }
}

// ---------------- launch ----------------

extern "C" void kernel_launch(void* const* d_in, const int* in_sizes, int n_in,
                              void* d_out, int out_size, void* d_ws, size_t ws_size,
                              hipStream_t stream) {
  const float* x    = (const float*)d_in[0];   // (8, 512, 2048)
  const float* W    = (const float*)d_in[1];   // (4096, 512)
  const float* bias = (const float*)d_in[2];   // (512)
  float* y          = (float*)d_out;           // (8, 512, 2048)

  unsigned short* xtp = (unsigned short*)d_ws;                     // 16,842,752 B
  unsigned short* Wf  = (unsigned short*)((char*)d_ws +
                        (size_t)BATCH * LPAD * CIN * sizeof(unsigned short));

  prepass_kernel<<<512 + 1024, 256, 0, stream>>>(
      x, xtp, (const float4*)W, (u16x8_t*)Wf);
  conv_gemm_kernel<<<dim3(LLEN / 128, COUT / 128, BATCH), 512, 0, stream>>>(
      Wf, xtp, bias, y);
}